// Round 10
// baseline (99355.725 us; speedup 1.0000x reference)
//
#include <hip/hip_runtime.h>
#include <hip/hip_bf16.h>
#include <cstdint>
#include <cstddef>

#define TSEQ 2048
#define BB   32
#define UU   512
#define NCOL 1536
#define GB   64      // blocks (slots) per group per layer
#define RING 8       // h1 ring depth

static __device__ __forceinline__ float aload(const float* p) {
    return __int_as_float(__hip_atomic_load((const int*)p, __ATOMIC_RELAXED,
                                            __HIP_MEMORY_SCOPE_AGENT));
}
static __device__ __forceinline__ void astore(float* p, float v) {
    __hip_atomic_store((int*)p, __float_as_int(v), __ATOMIC_RELAXED,
                       __HIP_MEMORY_SCOPE_AGENT);
}
static __device__ __forceinline__ unsigned f2bfu(float f) {
    __hip_bfloat16 b = __float2bfloat16(f);
    unsigned short s;
    __builtin_memcpy(&s, &b, 2);
    return (unsigned)s;
}
static __device__ __forceinline__ float bflo(unsigned u) { return __uint_as_float(u << 16); }
static __device__ __forceinline__ float bfhi(unsigned u) { return __uint_as_float(u & 0xffff0000u); }
static __device__ __forceinline__ int swz512(int k) { return k ^ (((k >> 6) & 7) << 2); }

// ---- repetition macros: literal-constant indices everywhere ----------------
#define REP4(X, B)  X(B) X((B)+1) X((B)+2) X((B)+3)
#define REP16(X, B) REP4(X, B) REP4(X, (B)+4) REP4(X, (B)+8) REP4(X, (B)+12)
#define REP32(X)    REP16(X, 0) REP16(X, 16)
#define REPQ8(X)    X(0) X(4) X(8) X(12) X(16) X(20) X(24) X(28)
#define REPQ16(X)   REPQ8(X) X(32) X(36) X(40) X(44) X(48) X(52) X(56) X(60)

// ---------------------------------------------------------------------------
// fp32 GEMM for xp1 = x@k1 + b_in  (proven R3 kernel)
// ---------------------------------------------------------------------------
__global__ __launch_bounds__(256)
void gemm_bias(const float* __restrict__ A, const float* __restrict__ W,
               const float* __restrict__ bias, float* __restrict__ C,
               int M, int N, int K)
{
    __shared__ float As[16][68];
    __shared__ float Bs[16][64];

    const int tid = threadIdx.x;
    const int tx = tid & 15, ty = tid >> 4;
    const int m0 = blockIdx.y * 64, n0 = blockIdx.x * 64;

    float acc[4][4] = {};

    for (int k0 = 0; k0 < K; k0 += 16) {
        {
            int r  = tid >> 2;
            int kq = (tid & 3) * 4;
            float4 av = *(const float4*)&A[(size_t)(m0 + r) * K + k0 + kq];
            As[kq + 0][r] = av.x;
            As[kq + 1][r] = av.y;
            As[kq + 2][r] = av.z;
            As[kq + 3][r] = av.w;
        }
        {
            int kk = tid >> 4;
            int n  = (tid & 15) * 4;
            *(float4*)&Bs[kk][n] = *(const float4*)&W[(size_t)(k0 + kk) * N + n0 + n];
        }
        __syncthreads();

        #pragma unroll
        for (int kk = 0; kk < 16; ++kk) {
            float av0 = As[kk][ty * 4 + 0];
            float av1 = As[kk][ty * 4 + 1];
            float av2 = As[kk][ty * 4 + 2];
            float av3 = As[kk][ty * 4 + 3];
            float4 bv = *(const float4*)&Bs[kk][tx * 4];
            acc[0][0] = fmaf(av0, bv.x, acc[0][0]);
            acc[0][1] = fmaf(av0, bv.y, acc[0][1]);
            acc[0][2] = fmaf(av0, bv.z, acc[0][2]);
            acc[0][3] = fmaf(av0, bv.w, acc[0][3]);
            acc[1][0] = fmaf(av1, bv.x, acc[1][0]);
            acc[1][1] = fmaf(av1, bv.y, acc[1][1]);
            acc[1][2] = fmaf(av1, bv.z, acc[1][2]);
            acc[1][3] = fmaf(av1, bv.w, acc[1][3]);
            acc[2][0] = fmaf(av2, bv.x, acc[2][0]);
            acc[2][1] = fmaf(av2, bv.y, acc[2][1]);
            acc[2][2] = fmaf(av2, bv.z, acc[2][2]);
            acc[2][3] = fmaf(av2, bv.w, acc[2][3]);
            acc[3][0] = fmaf(av3, bv.x, acc[3][0]);
            acc[3][1] = fmaf(av3, bv.y, acc[3][1]);
            acc[3][2] = fmaf(av3, bv.z, acc[3][2]);
            acc[3][3] = fmaf(av3, bv.w, acc[3][3]);
        }
        __syncthreads();
    }

    float4 bb = *(const float4*)&bias[n0 + tx * 4];
    #pragma unroll
    for (int i = 0; i < 4; ++i) {
        float4 v;
        v.x = acc[i][0] + bb.x;
        v.y = acc[i][1] + bb.y;
        v.z = acc[i][2] + bb.z;
        v.w = acc[i][3] + bb.w;
        *(float4*)&C[(size_t)(m0 + ty * 4 + i) * N + n0 + tx * 4] = v;
    }
}

// ---------------------------------------------------------------------------
// Fused 2-layer GRU v2: 512 blocks x 1024 threads (2 blocks/CU, 32 waves/CU).
// Block (g,slot) owns 8 hidden units (u0 = slot*8) for BOTH layers:
//   tid<512  = role A: layer-1 scan (step i).   24 cols, 16 j-slices of k=32
//              -> 16 packed weight regs/thread (rk1).
//   tid>=512 = role C: layer-2 scan (step i-1). R-pass (rk2 x h2) and X-pass
//              (k2 x h1) on DISJOINT threads: 48 vcols x 8 j-slices of k=64
//              -> 32 packed weight regs/thread.
// Fit-in-64-VGPR by design: the allocator pins 64 VGPRs for these kernels
// (R4-R9 evidence: read:write scratch asymmetry = weight reload, 100+ GB);
// waves_per_eu(8) makes <=64 a hard guarantee so 2-block/CU residency (and
// thus the flag protocol) cannot deadlock.
// Cross-block exchange via RELAXED AGENT atomics (no fences); __syncthreads()
// drains vmcnt before flag posts. A/C halves are lockstep within a block, so
// inter-block drift <= 1 iteration; RING=8 is ample.
// ---------------------------------------------------------------------------
__global__ __attribute__((amdgpu_waves_per_eu(8))) __launch_bounds__(1024)
void gru_fused(const float* __restrict__ xp1,  const float* __restrict__ h0,
               const float* __restrict__ rk1,  const float* __restrict__ b1,
               const float* __restrict__ k2,   const float* __restrict__ rk2,
               const float* __restrict__ b2,
               float* h1ring,                 // [RING][BB][UU]
               float* hp2,                    // [2][BB][UU]
               int* aflags, int* cflags,      // [512] each, zeroed
               float* __restrict__ out2, float* __restrict__ state1,
               float* __restrict__ state2)
{
    __shared__ float hl1[4][512];        // h1[i-1] (shared by A and C)
    __shared__ float hl2[4][512];        // h2[i-2] (C)
    __shared__ float xp[2][96];          // xp1 slices (A), dbuf
    __shared__ float innRA[24][4];
    __shared__ float innRC[24][4];
    __shared__ float innXC[24][4];

    const int tid  = threadIdx.x;
    const int lb   = blockIdx.x;               // 0..511
    const int g    = lb & 7, slot = lb >> 3;   // slot 0..63
    const int u0   = slot * 8, b0 = g * 4;
    const bool isA = (tid < 512);
    const int ht   = isA ? tid : (tid - 512);  // 0..511

    // A dot mapping: vcA 0..23 (3 gates x 8 units), j16 0..15, k-slice 32
    const int vcA   = ht >> 4;
    const int j16   = ht & 15;
    const int kbA   = j16 * 32;
    const int maskA = ((j16 >> 1) & 7) << 2;
    // C dot mapping: vcC 0..47 (R:0-23, X:24-47), jC 0..7, k-slice 64
    const int vcC   = ht >> 3;
    const int jC    = ht & 7;
    const int kbC   = jC * 64;
    const int maskC = jC << 2;
    const bool isX  = (vcC >= 24);
    const int c24   = isX ? (vcC - 24) : vcC;

    // ---- weights: A uses w[0..15], C uses w[0..31] ----
    unsigned w[32];
#define LW(M) w[(M)] = f2bfu(rbW[(size_t)(2*(M)) * NCOL]) \
                   | (f2bfu(rbW[(size_t)(2*(M)+1) * NCOL]) << 16);
    if (isA) {
        if (vcA < 24) {
            const int colA = (vcA >> 3) * UU + u0 + (vcA & 7);
            const float* rbW = rk1 + (size_t)kbA * NCOL + colA;
            REP16(LW, 0)
        }
    } else {
        if (vcC < 48) {
            const int colC = (c24 >> 3) * UU + u0 + (c24 & 7);
            const float* rbW = (isX ? k2 : rk2) + (size_t)kbC * NCOL + colC;
            REP32(LW)
        }
    }
#undef LW

    // ---- biases (gate threads: ht<32, 4 rows x 8 units) ----
    float bz = 0, brr = 0, bh = 0, b2z = 0, b2r = 0, b2h = 0;
    if (ht < 32) {
        int iu = ht & 7;
        if (isA) {
            bz  = b1[NCOL + u0 + iu];
            brr = b1[NCOL + UU + u0 + iu];
            bh  = b1[NCOL + 2 * UU + u0 + iu];
        } else {
            bz  = b2[NCOL + u0 + iu];
            brr = b2[NCOL + UU + u0 + iu];
            bh  = b2[NCOL + 2 * UU + u0 + iu];
            b2z = b2[u0 + iu];
            b2r = b2[UU + u0 + iu];
            b2h = b2[2 * UU + u0 + iu];
        }
    }

    // ---- prefill xp[0] with t=0 slice (A threads 384..479: 96 values) ----
    if (isA && ht >= 384 && ht < 480) {
        int p = ht - 384;
        int cc = p >> 2, b = p & 3;
        xp[0][p] = xp1[((size_t)(b0 + b) * TSEQ + 0) * NCOL
                       + (cc >> 3) * UU + u0 + (cc & 7)];
    }
    __syncthreads();

    for (int i = 0; i <= TSEQ; ++i) {
        // ---- poll phase ----
        if (i > 0) {
            if (isA) {
                if (ht < 64 && i < TSEQ) {
                    const int* fp = &aflags[g * GB + ht];
                    while (!__all(__hip_atomic_load(fp, __ATOMIC_RELAXED,
                                  __HIP_MEMORY_SCOPE_AGENT) >= i))
                        __builtin_amdgcn_s_sleep(1);
                }
            } else {
                if (ht < 64) {
                    const int* fp = &cflags[g * GB + ht];
                    while (!__all(__hip_atomic_load(fp, __ATOMIC_RELAXED,
                                  __HIP_MEMORY_SCOPE_AGENT) >= i - 1))
                        __builtin_amdgcn_s_sleep(1);
                } else if (ht < 128) {
                    const int* fp = &aflags[g * GB + (ht - 64)];
                    while (!__all(__hip_atomic_load(fp, __ATOMIC_RELAXED,
                                  __HIP_MEMORY_SCOPE_AGENT) >= i))
                        __builtin_amdgcn_s_sleep(1);
                }
            }
        }
        __syncthreads();

        // ---- stage hl1 <- h1[i-1] (h0 at i==0); all 1024 threads ----
        {
            const float* hs = (i == 0) ? h0
                            : (h1ring + (size_t)((i - 1) & 7) * BB * UU);
            #pragma unroll
            for (int q = 0; q < 2; ++q) {
                int idx = q * 1024 + tid;
                int row = idx >> 9, k = idx & 511;
                float v = (i == 0) ? hs[(size_t)(b0 + row) * UU + k]
                                   : aload(&hs[(size_t)(b0 + row) * UU + k]);
                hl1[row][swz512(k)] = v;
            }
        }
        // ---- stage hl2 <- h2[i-2] (h0 at i==1); C half ----
        if (!isA && i >= 1) {
            const float* hs2 = hp2 + (size_t)(i & 1) * BB * UU;
            #pragma unroll
            for (int q = 0; q < 4; ++q) {
                int idx = q * 512 + ht;
                int row = idx >> 9, k = idx & 511;
                float v = (i == 1) ? h0[(size_t)(b0 + row) * UU + k]
                                   : aload(&hs2[(size_t)(b0 + row) * UU + k]);
                hl2[row][swz512(k)] = v;
            }
        }
        __syncthreads();

        // ---- work phase ----
        if (isA) {
            if (i < TSEQ) {
                if (vcA < 24) {
                    float a0 = 0, a1 = 0, a2 = 0, a3 = 0;
#define STEPA(Q) { \
    const int p_ = kbA + ((Q) ^ maskA); \
    float4 v0 = *(const float4*)&hl1[0][p_]; \
    float4 v1 = *(const float4*)&hl1[1][p_]; \
    float4 v2 = *(const float4*)&hl1[2][p_]; \
    float4 v3 = *(const float4*)&hl1[3][p_]; \
    unsigned wa = w[(Q) >> 1], wb_ = w[((Q) >> 1) + 1]; \
    float w0 = bflo(wa), w1 = bfhi(wa), w2 = bflo(wb_), w3 = bfhi(wb_); \
    a0 = fmaf(w0, v0.x, a0); a1 = fmaf(w0, v1.x, a1); \
    a2 = fmaf(w0, v2.x, a2); a3 = fmaf(w0, v3.x, a3); \
    a0 = fmaf(w1, v0.y, a0); a1 = fmaf(w1, v1.y, a1); \
    a2 = fmaf(w1, v2.y, a2); a3 = fmaf(w1, v3.y, a3); \
    a0 = fmaf(w2, v0.z, a0); a1 = fmaf(w2, v1.z, a1); \
    a2 = fmaf(w2, v2.z, a2); a3 = fmaf(w2, v3.z, a3); \
    a0 = fmaf(w3, v0.w, a0); a1 = fmaf(w3, v1.w, a1); \
    a2 = fmaf(w3, v2.w, a2); a3 = fmaf(w3, v3.w, a3); }
                    REPQ8(STEPA)
                    #pragma unroll
                    for (int m = 1; m < 16; m <<= 1) {
                        a0 += __shfl_xor(a0, m); a1 += __shfl_xor(a1, m);
                        a2 += __shfl_xor(a2, m); a3 += __shfl_xor(a3, m);
                    }
                    if (j16 == 0) {
                        innRA[vcA][0] = a0; innRA[vcA][1] = a1;
                        innRA[vcA][2] = a2; innRA[vcA][3] = a3;
                    }
                } else if (ht >= 384 && ht < 480 && i + 1 < TSEQ) {
                    int p = ht - 384, nb = (i + 1) & 1;
                    int cc = p >> 2, b = p & 3;
                    xp[nb][p] = xp1[((size_t)(b0 + b) * TSEQ + (i + 1)) * NCOL
                                    + (cc >> 3) * UU + u0 + (cc & 7)];
                }
            }
        } else if (i >= 1 && vcC < 48) {
            const float (*hs)[512] = isX ? hl1 : hl2;
            float a0 = 0, a1 = 0, a2 = 0, a3 = 0;
#define STEPC(Q) { \
    const int p_ = kbC + ((Q) ^ maskC); \
    float4 v0 = *(const float4*)&hs[0][p_]; \
    float4 v1 = *(const float4*)&hs[1][p_]; \
    float4 v2 = *(const float4*)&hs[2][p_]; \
    float4 v3 = *(const float4*)&hs[3][p_]; \
    unsigned wa = w[(Q) >> 1], wb_ = w[((Q) >> 1) + 1]; \
    float w0 = bflo(wa), w1 = bfhi(wa), w2 = bflo(wb_), w3 = bfhi(wb_); \
    a0 = fmaf(w0, v0.x, a0); a1 = fmaf(w0, v1.x, a1); \
    a2 = fmaf(w0, v2.x, a2); a3 = fmaf(w0, v3.x, a3); \
    a0 = fmaf(w1, v0.y, a0); a1 = fmaf(w1, v1.y, a1); \
    a2 = fmaf(w1, v2.y, a2); a3 = fmaf(w1, v3.y, a3); \
    a0 = fmaf(w2, v0.z, a0); a1 = fmaf(w2, v1.z, a1); \
    a2 = fmaf(w2, v2.z, a2); a3 = fmaf(w2, v3.z, a3); \
    a0 = fmaf(w3, v0.w, a0); a1 = fmaf(w3, v1.w, a1); \
    a2 = fmaf(w3, v2.w, a2); a3 = fmaf(w3, v3.w, a3); }
            REPQ16(STEPC)
            #pragma unroll
            for (int m = 1; m < 8; m <<= 1) {
                a0 += __shfl_xor(a0, m); a1 += __shfl_xor(a1, m);
                a2 += __shfl_xor(a2, m); a3 += __shfl_xor(a3, m);
            }
            if (jC == 0) {
                float (*inn)[4] = isX ? innXC : innRC;
                inn[c24][0] = a0; inn[c24][1] = a1;
                inn[c24][2] = a2; inn[c24][3] = a3;
            }
        }
        __syncthreads();

        // ---- gates (32 threads per half: 4 rows x 8 units) ----
        if (isA) {
            if (i < TSEQ && ht < 32) {
                int bl = ht >> 3, iu = ht & 7, ug = u0 + iu;
                float rz = innRA[iu][bl]      + bz;
                float rr = innRA[8 + iu][bl]  + brr;
                float rh = innRA[16 + iu][bl] + bh;
                const float* xv = xp[i & 1];
                float xz = xv[iu * 4 + bl];
                float xr = xv[(8 + iu) * 4 + bl];
                float xh = xv[(16 + iu) * 4 + bl];
                float z  = 1.f / (1.f + expf(-(xz + rz)));
                float r  = 1.f / (1.f + expf(-(xr + rr)));
                float hh = tanhf(xh + r * rh);
                float hold = hl1[bl][swz512(ug)];
                float hnew = z * hold + (1.f - z) * hh;
                astore(h1ring + (size_t)(i & 7) * BB * UU
                              + (size_t)(b0 + bl) * UU + ug, hnew);
                if (i == TSEQ - 1) state1[(size_t)(b0 + bl) * UU + ug] = hnew;
            }
        } else if (i >= 1 && ht < 32) {
            int tc = i - 1;
            int bl = ht >> 3, iu = ht & 7, ug = u0 + iu;
            float rz = innRC[iu][bl]      + bz;
            float rr = innRC[8 + iu][bl]  + brr;
            float rh = innRC[16 + iu][bl] + bh;
            float xz = innXC[iu][bl]      + b2z;
            float xr = innXC[8 + iu][bl]  + b2r;
            float xh = innXC[16 + iu][bl] + b2h;
            float z  = 1.f / (1.f + expf(-(xz + rz)));
            float r  = 1.f / (1.f + expf(-(xr + rr)));
            float hh = tanhf(xh + r * rh);
            float hold = hl2[bl][swz512(ug)];
            float hnew = z * hold + (1.f - z) * hh;
            astore(hp2 + (size_t)(tc & 1) * BB * UU
                       + (size_t)(b0 + bl) * UU + ug, hnew);
            out2[((size_t)(b0 + bl) * TSEQ + tc) * UU + ug] = hnew;
            if (tc == TSEQ - 1) state2[(size_t)(b0 + bl) * UU + ug] = hnew;
        }
        __syncthreads();   // drains vmcnt: all h stores at MALL before flags

        if (tid == 0 && i < TSEQ)
            __hip_atomic_store(&aflags[g * GB + slot], i + 1,
                               __ATOMIC_RELAXED, __HIP_MEMORY_SCOPE_AGENT);
        if (tid == 512 && i >= 1)
            __hip_atomic_store(&cflags[g * GB + slot], i,
                               __ATOMIC_RELAXED, __HIP_MEMORY_SCOPE_AGENT);
    }
}

// ---------------------------------------------------------------------------
extern "C" void kernel_launch(void* const* d_in, const int* in_sizes, int n_in,
                              void* d_out, int out_size, void* d_ws, size_t ws_size,
                              hipStream_t stream)
{
    const float* x      = (const float*)d_in[0];
    const float* hidden = (const float*)d_in[1];
    const float* k1     = (const float*)d_in[2];
    const float* rk1    = (const float*)d_in[3];
    const float* b1     = (const float*)d_in[4];
    const float* k2     = (const float*)d_in[5];
    const float* rk2    = (const float*)d_in[6];
    const float* b2     = (const float*)d_in[7];

    const int M = BB * TSEQ;                      // 65536
    const size_t XPROJ_ELEMS = (size_t)M * NCOL;

    float* xp1    = (float*)d_ws;                         // M*NCOL
    float* h1ring = xp1 + XPROJ_ELEMS;                    // RING*BB*UU
    float* hp2    = h1ring + (size_t)RING * BB * UU;      // 2*BB*UU
    int*   aflags = (int*)(hp2 + 2 * (size_t)BB * UU);
    int*   cflags = aflags + 512;

    size_t need = (XPROJ_ELEMS + (size_t)(RING + 2) * BB * UU) * sizeof(float)
                + 1024 * sizeof(int);
    if (ws_size < need) return;

    float* out2   = (float*)d_out;
    float* state1 = out2 + (size_t)BB * TSEQ * UU;
    float* state2 = state1 + BB * UU;

    hipMemsetAsync(aflags, 0, 1024 * sizeof(int), stream);

    dim3 ggrid(NCOL / 64, M / 64);
    gemm_bias<<<ggrid, 256, 0, stream>>>(x, k1, b1, xp1, M, NCOL, 256);

    gru_fused<<<512, 1024, 0, stream>>>(xp1, hidden, rk1, b1, k2, rk2, b2,
                                        h1ring, hp2, aflags, cflags,
                                        out2, state1, state2);
}

// Round 13
// 61249.390 us; speedup vs baseline: 1.6222x; 1.6222x over previous
//
#include <hip/hip_runtime.h>
#include <hip/hip_bf16.h>
#include <cstdint>
#include <cstddef>

#define TSEQ 2048
#define BB   32
#define DD   256
#define UU   512
#define NCOL 1536
#define RING 8
#define HS   ((size_t)BB * UU)
#define GUARD (1 << 21)

static __device__ __forceinline__ float aload(const float* p) {
    return __int_as_float(__hip_atomic_load((const int*)p, __ATOMIC_RELAXED,
                                            __HIP_MEMORY_SCOPE_AGENT));
}
static __device__ __forceinline__ void astore(float* p, float v) {
    __hip_atomic_store((int*)p, __float_as_int(v), __ATOMIC_RELAXED,
                       __HIP_MEMORY_SCOPE_AGENT);
}
static __device__ __forceinline__ unsigned f2bfu(float f) {
    __hip_bfloat16 b = __float2bfloat16(f);
    unsigned short s;
    __builtin_memcpy(&s, &b, 2);
    return (unsigned)s;
}
static __device__ __forceinline__ float bflo(unsigned u) { return __uint_as_float(u << 16); }
static __device__ __forceinline__ float bfhi(unsigned u) { return __uint_as_float(u & 0xffff0000u); }
static __device__ __forceinline__ int swz4(int k) { return k ^ (((k >> 7) & 3) << 2); }

#define REP4(X, B)  X(B) X((B)+1) X((B)+2) X((B)+3)
#define REP16(X, B) REP4(X, B) REP4(X, (B)+4) REP4(X, (B)+8) REP4(X, (B)+12)
#define REP64(X)    REP16(X, 0) REP16(X, 16) REP16(X, 32) REP16(X, 48)
#define DOT32(X)    X(0) X(4) X(8) X(12) X(16) X(20) X(24) X(28) \
                    X(32) X(36) X(40) X(44) X(48) X(52) X(56) X(60) \
                    X(64) X(68) X(72) X(76) X(80) X(84) X(88) X(92) \
                    X(96) X(100) X(104) X(108) X(112) X(116) X(120) X(124)

// ---------------------------------------------------------------------------
// Role-free fused 2-layer GRU scan. 512 blocks x 512 threads, one code path.
// Layer identity is per-block DATA (pointers/strides), never a duplicated
// body (R4-R10 lesson: dual-body kernels get their weight arrays demoted to
// scratch; single-body R3/R12 allocate honestly).
//  bid<256 (L1): S=[h1[t-1]; xpad(x[t])], W=[rk1; k1pad], biases b1.
//  bid>=256(L2): S=[h2[t-1]; h1[t]],      W=[rk2; k2],    biases b2.
// K=1024 GEMV, two accumulators (Lo = recurrent part -> *r inside tanh;
// Hi = input part -> added outside) == Keras reset_after exactly.
// __launch_bounds__(512,4): min 4 waves/EU -> hard 128-VGPR cap -> with
// 18 KB LDS, 2 blocks/CU residency GUARANTEED (R12 failed here: (512,2)
// allowed >128 VGPR -> 1 block/CU -> half the grid unresident -> fuse).
// Protocol (relaxed AGENT atomics at the coherence point, no fences;
// __syncthreads() drains vmcnt before each post; posts unconditional):
//   A@i waits {aflags>=i ; cflags>=i-6 (ring guard)}
//   C@i waits {cflags>=i ; aflags>=i (producer)}          -> acyclic, RING=8.
// Deadlock fuse: polls give up after GUARD spins -> block exits -> fast
// visible failure instead of a 600 s timeout.
// ---------------------------------------------------------------------------
__global__ __launch_bounds__(512, 4)
void gru_scan2(const float* __restrict__ x,
               const float* __restrict__ rk1, const float* __restrict__ k1,
               const float* __restrict__ b1,
               const float* __restrict__ rk2, const float* __restrict__ k2,
               const float* __restrict__ b2,
               float* h1ring, float* h2ring,      // [RING][BB][UU] each
               const float* __restrict__ zerobuf, // >=2048 f32 zeros
               int* aflags, int* cflags,          // [256] each, zeroed
               float* __restrict__ out2, float* __restrict__ state1,
               float* __restrict__ state2)
{
    __shared__ float hl[8][512];        // rows 0-3 = S-lo, 4-7 = S-hi
    __shared__ float inn[2][48][4];     // [half][col][row]
    __shared__ int   sdead;

    const int tid  = threadIdx.x;
    const int bid  = blockIdx.x;
    const bool isA = (bid < 256);
    const int lb   = isA ? bid : (bid - 256);
    const int g    = lb & 7, slot = lb >> 3;
    const int u0   = slot * 16, b0 = g * 4;

    // ---- per-block role data ----
    float*       ownring = isA ? h1ring : h2ring;
    const float* binp    = isA ? b1 : b2;
    const float* brecp   = binp + NCOL;
    int*         postf   = (isA ? aflags : cflags) + g * 32 + slot;
    const int*   pOwn    = (isA ? aflags : cflags) + g * 32;
    const int*   pPar    = (isA ? cflags : aflags) + g * 32;
    const int    o2      = isA ? -6 : 0;
    const int    tofs    = isA ? 0 : -1;
    float*       statep  = isA ? state1 : state2;

    const int c     = tid >> 3;       // 0..63 (0..47 = dot cols)
    const int j     = tid & 7;
    const int jj    = j & 3;
    const int hsel  = j >> 2;         // 0 = Lo half, 1 = Hi half
    const int hb    = hsel * 4;
    const int jsw   = jj << 2;
    const int kbase = jj * 128;

    // ---- weights: 64 bf16-packed words (128 k-rows) per dot thread ----
    unsigned w[64];
    if (c < 48) {
        const int col = (c >> 4) * UU + u0 + (c & 15);
        const float* wsrc;
        size_t wst;
        if (hsel == 0) {
            wsrc = (isA ? rk1 : rk2) + (size_t)kbase * NCOL + col;
            wst = NCOL;
        } else if (!isA) {
            wsrc = k2 + (size_t)kbase * NCOL + col;
            wst = NCOL;
        } else if (kbase < DD) {
            wsrc = k1 + (size_t)kbase * NCOL + col;
            wst = NCOL;
        } else {
            wsrc = zerobuf + col;    // zeros (k1 pad rows 256..511)
            wst = 0;
        }
#define LW(M) w[(M)] = f2bfu(wsrc[(size_t)(2*(M)) * wst]) \
                   | (f2bfu(wsrc[(size_t)(2*(M)+1) * wst]) << 16);
        REP64(LW)
#undef LW
    }

    // ---- gate biases (threads 0..63) ----
    float biz = 0, bir = 0, bih = 0, brz = 0, brr = 0, brh = 0;
    if (tid < 64) {
        int iu = tid & 15;
        biz = binp[u0 + iu];
        bir = binp[UU + u0 + iu];
        bih = binp[2 * UU + u0 + iu];
        brz = brecp[u0 + iu];
        brr = brecp[UU + u0 + iu];
        brh = brecp[2 * UU + u0 + iu];
    }

    if (tid == 0) sdead = 0;
    __syncthreads();

    for (int i = 0; i <= TSEQ; ++i) {
        const int t = i + tofs;
        const bool tv = (t >= 0) & (t < TSEQ);

        // ---- poll (lanes 0-31: own group >= i; 32-63: partner >= i+o2) ----
        if (tid < 64) {
            const int* fp  = (tid < 32) ? (pOwn + tid) : (pPar + (tid - 32));
            const int  thr = (tid < 32) ? i : (i + o2);
            int guard = 0;
            while (!__all(__hip_atomic_load(fp, __ATOMIC_RELAXED,
                          __HIP_MEMORY_SCOPE_AGENT) >= thr)) {
                __builtin_amdgcn_s_sleep(1);
                if (++guard > GUARD) { sdead = 1; break; }
            }
        }
        __syncthreads();
        if (sdead) break;          // deadlock fuse: fast fail, not timeout

        // ---- stage S: Lo rows 0-3 (own ring), Hi rows 4-7 ----
        if (tv) {
            const float* slo = ownring + (size_t)((t - 1) & 7) * HS;
            #pragma unroll
            for (int q = 0; q < 4; ++q)
                hl[q][swz4(tid)] = aload(&slo[(size_t)(b0 + q) * UU + tid]);
            if (isA) {
                // x[t] rows, cached loads (read-only input), zero-padded
                #pragma unroll
                for (int q = 0; q < 4; ++q) {
                    float v = 0.f;
                    if (tid < DD)
                        v = x[((size_t)(b0 + q) * TSEQ + t) * DD + tid];
                    hl[4 + q][swz4(tid)] = v;
                }
            } else {
                const float* shi = h1ring + (size_t)(t & 7) * HS;
                #pragma unroll
                for (int q = 0; q < 4; ++q)
                    hl[4 + q][swz4(tid)] =
                        aload(&shi[(size_t)(b0 + q) * UU + tid]);
            }
        }
        __syncthreads();

        // ---- dual GEMV halves (384 dot threads) ----
        if (tv && c < 48) {
            float a0 = 0, a1 = 0, a2 = 0, a3 = 0;
#define DSTEP(Q) { \
    const int p_ = kbase + ((Q) ^ jsw); \
    float4 v0 = *(const float4*)&hl[hb + 0][p_]; \
    float4 v1 = *(const float4*)&hl[hb + 1][p_]; \
    float4 v2 = *(const float4*)&hl[hb + 2][p_]; \
    float4 v3 = *(const float4*)&hl[hb + 3][p_]; \
    unsigned wa = w[(Q) >> 1], wb_ = w[((Q) >> 1) + 1]; \
    float w0 = bflo(wa), w1 = bfhi(wa), w2 = bflo(wb_), w3 = bfhi(wb_); \
    a0 = fmaf(w0, v0.x, a0); a1 = fmaf(w0, v1.x, a1); \
    a2 = fmaf(w0, v2.x, a2); a3 = fmaf(w0, v3.x, a3); \
    a0 = fmaf(w1, v0.y, a0); a1 = fmaf(w1, v1.y, a1); \
    a2 = fmaf(w1, v2.y, a2); a3 = fmaf(w1, v3.y, a3); \
    a0 = fmaf(w2, v0.z, a0); a1 = fmaf(w2, v1.z, a1); \
    a2 = fmaf(w2, v2.z, a2); a3 = fmaf(w2, v3.z, a3); \
    a0 = fmaf(w3, v0.w, a0); a1 = fmaf(w3, v1.w, a1); \
    a2 = fmaf(w3, v2.w, a2); a3 = fmaf(w3, v3.w, a3); }
            DOT32(DSTEP)
#undef DSTEP
            a0 += __shfl_xor(a0, 1); a1 += __shfl_xor(a1, 1);
            a2 += __shfl_xor(a2, 1); a3 += __shfl_xor(a3, 1);
            a0 += __shfl_xor(a0, 2); a1 += __shfl_xor(a1, 2);
            a2 += __shfl_xor(a2, 2); a3 += __shfl_xor(a3, 2);
            if (jj == 0) {
                inn[hsel][c][0] = a0; inn[hsel][c][1] = a1;
                inn[hsel][c][2] = a2; inn[hsel][c][3] = a3;
            }
        }
        __syncthreads();

        // ---- gates (64 threads: 4 rows x 16 units) ----
        if (tv && tid < 64) {
            int bl = tid >> 4, iu = tid & 15, ug = u0 + iu;
            float loz = inn[0][iu][bl],      hiz = inn[1][iu][bl];
            float lor = inn[0][16 + iu][bl], hir = inn[1][16 + iu][bl];
            float loh = inn[0][32 + iu][bl], hih = inn[1][32 + iu][bl];
            float z = 1.f / (1.f + expf(-(hiz + biz + loz + brz)));
            float r = 1.f / (1.f + expf(-(hir + bir + lor + brr)));
            float hh = tanhf(hih + bih + r * (loh + brh));
            float hold = hl[bl][swz4(ug)];
            float hnew = z * hold + (1.f - z) * hh;
            astore(ownring + (size_t)(t & 7) * HS
                           + (size_t)(b0 + bl) * UU + ug, hnew);
            if (!isA)
                out2[((size_t)(b0 + bl) * TSEQ + t) * UU + ug] = hnew;
            if (t == TSEQ - 1) statep[(size_t)(b0 + bl) * UU + ug] = hnew;
        }
        __syncthreads();   // drains vmcnt: h stores at MALL before flag

        if (tid == 0)
            __hip_atomic_store(postf, i + 1, __ATOMIC_RELAXED,
                               __HIP_MEMORY_SCOPE_AGENT);
    }
}

// ---------------------------------------------------------------------------
extern "C" void kernel_launch(void* const* d_in, const int* in_sizes, int n_in,
                              void* d_out, int out_size, void* d_ws, size_t ws_size,
                              hipStream_t stream)
{
    const float* x      = (const float*)d_in[0];
    const float* hidden = (const float*)d_in[1];
    const float* k1     = (const float*)d_in[2];
    const float* rk1    = (const float*)d_in[3];
    const float* b1     = (const float*)d_in[4];
    const float* k2     = (const float*)d_in[5];
    const float* rk2    = (const float*)d_in[6];
    const float* b2     = (const float*)d_in[7];

    float* h1ring  = (float*)d_ws;                        // RING*HS
    float* h2ring  = h1ring + RING * HS;                  // RING*HS
    float* zerobuf = h2ring + RING * HS;                  // 2048
    int*   aflags  = (int*)(zerobuf + 2048);
    int*   cflags  = aflags + 256;

    size_t need = (2 * RING * HS + 2048) * sizeof(float) + 512 * sizeof(int);
    if (ws_size < need) return;

    float* out2   = (float*)d_out;
    float* state1 = out2 + (size_t)BB * TSEQ * UU;
    float* state2 = state1 + HS;

    hipMemsetAsync(aflags, 0, 512 * sizeof(int), stream);
    hipMemsetAsync(zerobuf, 0, 2048 * sizeof(float), stream);
    // seed both rings' slot 7 with h0 (the t = -1 state)
    hipMemcpyAsync(h1ring + 7 * HS, hidden, HS * sizeof(float),
                   hipMemcpyDeviceToDevice, stream);
    hipMemcpyAsync(h2ring + 7 * HS, hidden, HS * sizeof(float),
                   hipMemcpyDeviceToDevice, stream);

    gru_scan2<<<512, 512, 0, stream>>>(x, rk1, k1, b1, rk2, k2, b2,
                                       h1ring, h2ring, zerobuf,
                                       aflags, cflags, out2, state1, state2);
}